// Round 1
// 195.374 us; speedup vs baseline: 1.1831x; 1.1831x over previous
//
#include <hip/hip_runtime.h>
#include <hip/hip_fp16.h>
#include <cstdint>
#include <cstddef>

#define T_DIM 5
#define F_DIM 8
#define Z_DIM 16
#define Y_DIM 96
#define X_DIM 96
#define NRAYS 32768
#define K_SAMP 128

// Pipeline:
//   prep_w    : wB f16 [p=ci/32][tap 27][zo 16][ci32]  (55296 halves) + bR f32[16] + loU/hiU init
//   transpose : inp f16 [t][y][x][ci=f*16+z]           (5,898,240 halves)
//   nearfar   : unchanged
//   conv_mfma : fld f32 [t][zo][y][x] = conv(inp) via v_mfma_f32_16x16x32_f16, bias fused
//   pack      : fld -> cellp (fp16 cell corners)        (unchanged)
//   render    : unchanged
//
// ws layout (f32 units):
//   fld   [0 .. 737,280)
//   inp   [737,280 .. 3,686,400)   (half*, dead after conv)
//   cellp [737,280 .. 3,686,400)   (overlaps dead inp; written by pack)
//   wB    [3,686,400 .. +27,648)   (half*)
//   bR    +32 | nearA +163,840 | farA +163,840 | loU/hiU +16

struct __align__(16) Cell { __half2 h0, h1, h2, h3; };

typedef __attribute__((ext_vector_type(4))) float     f32x4;
typedef __attribute__((ext_vector_type(8))) _Float16  f16x8;

__global__ __launch_bounds__(256) void prep_w_kernel(
        const float* __restrict__ w, const float* __restrict__ cb,
        const float* __restrict__ dw,
        __half* __restrict__ wB, float* __restrict__ bR,
        unsigned* loU, unsigned* hiU) {
    int i = blockIdx.x * 256 + threadIdx.x;          // 0 .. 55295 exactly
    if (i < 8) { loU[i] = 0x7F800000u; hiU[i] = 0u; }
    if (i < 16) {
        float s = 0.f;
        #pragma unroll
        for (int f = 0; f < 8; ++f) s += cb[f * 16 + i] * dw[f];
        bR[i] = s;
    }
    // idx = ((p*27 + tap)*16 + zo)*32 + cs ; ci = p*32 + cs
    int cs  = i & 31;
    int zo  = (i >> 5) & 15;
    int pt  = i >> 9;            // p*27 + tap, 0..107
    int p   = pt / 27;
    int tap = pt - p * 27;
    int ci  = p * 32 + cs;
    float s = 0.f;
    #pragma unroll
    for (int f = 0; f < 8; ++f)
        s += w[(size_t)((f * 16 + zo) * 128 + ci) * 27 + tap] * dw[f];
    wB[i] = __float2half(s);
}

// inp[((t*96+y)*96+x)*128 + f*16+z] = (half) vol[f][t][z][y][x]
__global__ __launch_bounds__(256) void transpose_vol_kernel(
        const float* __restrict__ xin, __half* __restrict__ inp) {
    __shared__ __half lds[96 * 136];                 // [x][ci], pad 136 for 16B-aligned reads
    int b = blockIdx.x;                              // 480 = 5*96
    int t = b / 96, y = b - (b / 96) * 96;
    for (int i = threadIdx.x; i < 12288; i += 256) { // 128 (f,z) rows x 96 x, coalesced reads
        int row = i / 96;
        int x   = i - row * 96;
        int f = row >> 4, z = row & 15;
        float v = xin[(((size_t)(f * 5 + t) * 16 + z) * 96 + y) * 96 + x];
        lds[x * 136 + row] = __float2half(v);
    }
    __syncthreads();
    __half* ob = inp + ((size_t)(t * 96 + y) * 96) * 128;
    for (int c = threadIdx.x; c < 1536; c += 256) {  // 96 x * 16 chunks of 16B, coalesced writes
        int x = c >> 4, sub = c & 15;
        uint4 v = *(const uint4*)(lds + x * 136 + sub * 8);
        *(uint4*)(ob + (size_t)x * 128 + sub * 8) = v;
    }
}

__global__ __launch_bounds__(256) void nearfar_kernel(
        const float* __restrict__ ro, const float* __restrict__ rd,
        float* __restrict__ nearA, float* __restrict__ farA,
        unsigned* loU, unsigned* hiU) {
    int gid = blockIdx.x * 256 + threadIdx.x;
    int t = gid / NRAYS;
    const float* o = ro + (size_t)gid * 3;
    const float* d = rd + (size_t)gid * 3;
    float ox = o[0], oy = o[1], oz = o[2];
    float dx = d[0], dy = d[1], dz = d[2];
    float t1x = (0.f - ox) / dx, t2x = (1.f - ox) / dx;
    float t1y = (0.f - oy) / dy, t2y = (1.f - oy) / dy;
    float t1z = (0.f - oz) / dz, t2z = (1.f - oz) / dz;
    float nr = fmaxf(fmaxf(fminf(t1x, t2x), fminf(t1y, t2y)), fminf(t1z, t2z));
    float fr = fminf(fminf(fmaxf(t1x, t2x), fmaxf(t1y, t2y)), fmaxf(t1z, t2z));
    nr = fmaxf(nr, 0.01f);
    fr = fmaxf(fr, nr + 1e-6f);
    nearA[gid] = nr;
    farA[gid]  = fr;
    float slast = fmaf(0.9921875f, fr - nr, nr);
    float mn = nr, mx = slast;
    #pragma unroll
    for (int off = 32; off > 0; off >>= 1) {
        mn = fminf(mn, __shfl_down(mn, off, 64));
        mx = fmaxf(mx, __shfl_down(mx, off, 64));
    }
    __shared__ float smn[4], smx[4];
    int w = threadIdx.x >> 6;
    if ((threadIdx.x & 63) == 0) { smn[w] = mn; smx[w] = mx; }
    __syncthreads();
    if (threadIdx.x == 0) {
        mn = fminf(fminf(smn[0], smn[1]), fminf(smn[2], smn[3]));
        mx = fmaxf(fmaxf(smx[0], smx[1]), fmaxf(smx[2], smx[3]));
        atomicMin(&loU[t], __float_as_uint(mn));
        atomicMax(&hiU[t], __float_as_uint(mx));
    }
}

// Block = (t, y-pair, 32-x seg), 128 thr (2 waves; wave w handles y = y0+w, two 16-x tiles).
// LDS: [12 rows = 3 t' x 4 y'][34 x (halo)][32 ci] f16, zero-padded halos -> branch-free taps.
// 4 ci-phases (32 ci each); weights as MFMA A operand (M = zo), input as B (N = x).
__global__ __launch_bounds__(128) void conv_mfma_kernel(
        const __half* __restrict__ inp, const __half* __restrict__ wB,
        const float* __restrict__ bR, float* __restrict__ fld) {
    // bijective XCD swizzle: 720 = 8 * 90; each XCD gets a contiguous chunk (<=2 t-slices).
    int bid = blockIdx.x;
    int wg  = (bid & 7) * 90 + (bid >> 3);
    int xs  = wg % 3;
    int rem = wg / 3;
    int yp  = rem % 48;
    int t   = rem / 48;
    int xseg = xs * 32, y0 = yp * 2;

    __shared__ __half lds[12 * 34 * 32];             // 26,112 B
    const int w    = threadIdx.x >> 6;               // 0..1 : output y = y0 + w
    const int lane = threadIdx.x & 63;
    const int l15  = lane & 15;
    const int ksub = lane >> 4;                      // 0..3 : k-subgroup (8 f16 each)

    f32x4 acc0 = {0.f, 0.f, 0.f, 0.f};
    f32x4 acc1 = {0.f, 0.f, 0.f, 0.f};

    for (int p = 0; p < 4; ++p) {
        // ---- stage: 12 x 34 x 32 halves = 1632 chunks of 16B; zeros outside volume ----
        for (int c = threadIdx.x; c < 1632; c += 128) {
            int row = c / 136;                       // 34*4 chunks per row
            int r2  = c - row * 136;
            int xl  = r2 >> 2, sub = r2 & 3;
            int tt = t  + (row >> 2) - 1;
            int yy = y0 + (row & 3)  - 1;
            int xg = xseg + xl - 1;
            uint4 v = {0u, 0u, 0u, 0u};
            if ((unsigned)tt < 5u && (unsigned)yy < 96u && (unsigned)xg < 96u)
                v = *(const uint4*)(inp + ((((size_t)tt * 96 + yy) * 96 + xg) << 7)
                                        + (p << 5) + (sub << 3));
            *(uint4*)(lds + (size_t)c * 8) = v;
        }
        __syncthreads();

        // ---- compute: 27 taps x (1 L1 weight load + 2 ds_read + 2 MFMA) ----
        const __half* wp_base = wB + (size_t)p * 13824 + l15 * 32 + ksub * 8; // p*27*512
        #pragma unroll
        for (int kt = 0; kt < 3; ++kt) {
            #pragma unroll
            for (int ky = 0; ky < 3; ++ky) {
                const __half* lrow = lds + (kt * 4 + w + ky) * 1088 + ksub * 8;
                #pragma unroll
                for (int kx = 0; kx < 3; ++kx) {
                    int tap = (kt * 3 + ky) * 3 + kx;
                    f16x8 aw = *(const f16x8*)(wp_base + tap * 512);
                    f16x8 b0 = *(const f16x8*)(lrow + (l15 + kx) * 32);
                    acc0 = __builtin_amdgcn_mfma_f32_16x16x32_f16(aw, b0, acc0, 0, 0, 0);
                    f16x8 b1 = *(const f16x8*)(lrow + (l15 + kx + 16) * 32);
                    acc1 = __builtin_amdgcn_mfma_f32_16x16x32_f16(aw, b1, acc1, 0, 0, 0);
                }
            }
        }
        __syncthreads();
    }

    // ---- epilogue: D[row=zo=(ksub*4+r)][col=x=l15]; lane-contiguous 64B stores ----
    int yw = y0 + w;
    #pragma unroll
    for (int r = 0; r < 4; ++r) {
        int zo = ksub * 4 + r;
        float bz = bR[zo];
        size_t o = (((size_t)t * 16 + zo) * 96 + yw) * 96 + xseg + l15;
        fld[o]      = acc0[r] + bz;
        fld[o + 16] = acc1[r] + bz;
    }
}

// cellp[t][z][y][x] = 8 fp16 corners of cell (z..z+1, y..y+1, x..x+1), clamped at edges.
__global__ __launch_bounds__(256) void pack_kernel(
        const float* __restrict__ fld, Cell* __restrict__ cellp) {
    int i = blockIdx.x * 256 + threadIdx.x;
    if (i >= 737280) return;
    int x = i % 96;
    int r = i / 96;
    int y = r % 96;
    int r2 = r / 96;
    int z = r2 % 16;
    int t = r2 / 16;
    const float* ft = fld + (size_t)t * 147456;
    int xp = min(x + 1, 95);
    int yr0 = y * 96, yr1 = min(y + 1, 95) * 96;
    int zr0 = z * 9216, zr1 = min(z + 1, 15) * 9216;
    float c000 = ft[zr0 + yr0 + x], c001 = ft[zr0 + yr0 + xp];
    float c010 = ft[zr0 + yr1 + x], c011 = ft[zr0 + yr1 + xp];
    float c100 = ft[zr1 + yr0 + x], c101 = ft[zr1 + yr0 + xp];
    float c110 = ft[zr1 + yr1 + x], c111 = ft[zr1 + yr1 + xp];
    Cell cl;
    cl.h0 = __floats2half2_rn(c000, c001);
    cl.h1 = __floats2half2_rn(c010, c011);
    cl.h2 = __floats2half2_rn(c100, c101);
    cl.h3 = __floats2half2_rn(c110, c111);
    cellp[i] = cl;
}

// 4 lanes per ray, 32 samples each. XCD-affinity block remap as before.
__global__ __launch_bounds__(256) void render_kernel(
        const float* __restrict__ ro, const float* __restrict__ rd,
        const Cell* __restrict__ cellp,
        const float* __restrict__ nearA, const float* __restrict__ farA,
        const unsigned* __restrict__ loU, const unsigned* __restrict__ hiU,
        const float* __restrict__ dens_b, float* __restrict__ out) {
    int b = blockIdx.x;                 // 0..2559
    int b7 = b & 7, bhi = b >> 3;       // bhi 0..319
    int t, seg;
    if (b7 < 5) { t = b7; seg = bhi; }
    else { int j = (b7 - 5) * 320 + bhi; t = j / 192; seg = 320 + j % 192; }
    int c = threadIdx.x & 3;
    int ray = t * NRAYS + seg * 64 + (threadIdx.x >> 2);

    const float* o = ro + (size_t)ray * 3;
    const float* d = rd + (size_t)ray * 3;
    float ox = o[0], oy = o[1], oz = o[2];
    float dx = d[0], dy = d[1], dz = d[2];
    float nr = nearA[ray], fr = farA[ray];
    float span = fr - nr;
    const Cell* vt = cellp + (size_t)t * 147456;
    float db = dens_b[0];

    float step = span * 0.0078125f;
    float s  = fmaf((float)(c * 32), step, nr);
    float mid = s + 0.5f * step;
    float px = fmaf(dx, mid, ox);
    float py = fmaf(dy, mid, oy);
    float pz = fmaf(dz, mid, oz);
    float ddx = dx * step, ddy = dy * step, ddz = dz * step;

    float num = 0.f, den = 0.f, A = 0.f;
    float trans = 1.f;
    int pidx = -1;
    float2 f00 = {0.f, 0.f}, f01 = {0.f, 0.f}, f10 = {0.f, 0.f}, f11 = {0.f, 0.f};
    for (int kk = 0; kk < 32; ++kk) {
        float gx = fminf(fmaxf(px, 0.f), 1.f) * 95.f;
        float gy = fminf(fmaxf(py, 0.f), 1.f) * 95.f;
        float gz = fminf(fmaxf(pz, 0.f), 1.f) * 15.f;
        int x0 = min((int)gx, 94), y0 = min((int)gy, 94), z0 = min((int)gz, 14);
        float fx = gx - (float)x0, fy = gy - (float)y0, fz = gz - (float)z0;

        int idx = z0 * 9216 + y0 * 96 + x0;
        if (idx != pidx) {
            pidx = idx;
            Cell cl = vt[idx];
            f00 = __half22float2(cl.h0);
            f01 = __half22float2(cl.h1);
            f10 = __half22float2(cl.h2);
            f11 = __half22float2(cl.h3);
        }

        float v00 = f00.x + fx * (f00.y - f00.x);
        float v01 = f01.x + fx * (f01.y - f01.x);
        float v10 = f10.x + fx * (f10.y - f10.x);
        float v11 = f11.x + fx * (f11.y - f11.x);
        float v0  = v00 + fy * (v01 - v00);
        float v1  = v10 + fy * (v11 - v10);
        float pre = v0 + fz * (v1 - v0) + db;

        float u = __expf(-fabsf(pre));
        float dens = fmaxf(pre, 0.f) + __logf(1.f + u);   // softplus
        float dd = dens * step;
        float ex = __expf(-dd);
        float wgt = (1.f - ex) * trans;
        num = fmaf(wgt, s, num);
        den += wgt;
        trans *= ex;
        A += dd;
        s += step; px += ddx; py += ddy; pz += ddz;
    }
    int lane = threadIdx.x & 63;
    int q = lane & ~3;
    float A0 = __shfl(A, q,     64);
    float A1 = __shfl(A, q + 1, 64);
    float A2 = __shfl(A, q + 2, 64);
    float P = 0.f;
    if (c > 0) P += A0;
    if (c > 1) P += A1;
    if (c > 2) P += A2;
    float sc = __expf(-P);
    float numc = num * sc;
    float denc = den * sc;
    numc += __shfl_xor(numc, 1, 64);
    numc += __shfl_xor(numc, 2, 64);
    denc += __shfl_xor(denc, 1, 64);
    denc += __shfl_xor(denc, 2, 64);
    if (c == 0) {
        float depth = numc / (denc + 1e-10f);
        float lo = __uint_as_float(loU[t]);
        float hi = __uint_as_float(hiU[t]);
        depth = fminf(fmaxf(depth, lo), hi);
        out[ray] = depth;
    }
}

extern "C" void kernel_launch(void* const* d_in, const int* in_sizes, int n_in,
                              void* d_out, int out_size, void* d_ws, size_t ws_size,
                              hipStream_t stream) {
    const float* vol = (const float*)d_in[0];   // [1,8,5,16,96,96]
    const float* ro  = (const float*)d_in[1];   // [5,32768,3]
    const float* rd  = (const float*)d_in[2];   // [5,32768,3]
    const float* cw  = (const float*)d_in[3];   // [128,128,3,3,3]
    const float* cb  = (const float*)d_in[4];   // [128]
    const float* dw  = (const float*)d_in[5];   // [8,1]
    const float* dbp = (const float*)d_in[6];   // [1]
    float* out = (float*)d_out;                 // [5,32768,1] f32

    float* ws      = (float*)d_ws;
    float* fld     = ws;                                    // [0 .. 737,280)
    __half* inp    = (__half*)(ws + 737280);                // 5,898,240 halves
    Cell*  cellp   = (Cell*)(ws + 737280);                  // overlaps dead inp
    __half* wB     = (__half*)(ws + 737280 + 2949120);      // 55,296 halves
    float* bR      = ws + 737280 + 2949120 + 27648;         // 16 (+pad to 32)
    float* nearA   = bR + 32;                               // 163,840
    float* farA    = nearA + 163840;                        // 163,840
    unsigned* loU  = (unsigned*)(farA + 163840);            // 8
    unsigned* hiU  = loU + 8;                               // 8

    hipLaunchKernelGGL(prep_w_kernel, dim3(216), dim3(256), 0, stream,
                       cw, cb, dw, wB, bR, loU, hiU);
    hipLaunchKernelGGL(transpose_vol_kernel, dim3(480), dim3(256), 0, stream, vol, inp);
    hipLaunchKernelGGL(nearfar_kernel, dim3(640), dim3(256), 0, stream,
                       ro, rd, nearA, farA, loU, hiU);
    hipLaunchKernelGGL(conv_mfma_kernel, dim3(720), dim3(128), 0, stream,
                       inp, wB, bR, fld);
    hipLaunchKernelGGL(pack_kernel, dim3(2880), dim3(256), 0, stream, fld, cellp);
    hipLaunchKernelGGL(render_kernel, dim3(2560), dim3(256), 0, stream,
                       ro, rd, cellp, nearA, farA, loU, hiU, dbp, out);
}